// Round 8
// baseline (520.262 us; speedup 1.0000x reference)
//
#include <hip/hip_runtime.h>
#include <hip/hip_bf16.h>
#include <cstdint>

typedef __attribute__((ext_vector_type(8))) short short8;     // 8 bf16 frag (4 VGPRs)
typedef __attribute__((ext_vector_type(16))) float f32x16;    // 32x32 accumulator
typedef unsigned short us;

#define BIN_SHIFT 9
#define BIN_NODES 512
#define CAPB 12288   // per-bin capacity (mean 8163, +45 sigma)
#define EPB 4096     // edges per binA block

__device__ __forceinline__ float bflo(uint32_t u) { return __builtin_bit_cast(float, u << 16); }
__device__ __forceinline__ float bfhi(uint32_t u) { return __builtin_bit_cast(float, u & 0xffff0000u); }

__device__ __forceinline__ us f32_to_bf16_rne(float f) {
  uint32_t u = __builtin_bit_cast(uint32_t, f);
  u += 0x7fffu + ((u >> 16) & 1u);
  return (us)(u >> 16);
}

// split f32 into truncated-bf16 hi + bf16 lo (residual); hi+lo ~= f to ~2^-16 rel
__device__ __forceinline__ void split2(float f, us& h, us& l) {
  uint32_t u = __builtin_bit_cast(uint32_t, f);
  h = (us)(u >> 16);
  float fh = __builtin_bit_cast(float, u & 0xffff0000u);
  float r = f - fh;  // exact
  l = (us)(__builtin_bit_cast(uint32_t, r) >> 16);
}

// ---------------- pass A: bin packed (localdst<<23|src) by dst>>9, dense batched appends ----------------
__global__ __launch_bounds__(256) void k_binA(
    const int* __restrict__ src, const int* __restrict__ dst,
    uint32_t* __restrict__ binbuf, int* __restrict__ gcur, int E, int nbins) {
  __shared__ uint32_t stage[EPB];                    // 16 KB
  __shared__ int cnt[256], base[256], cur[256], gbase[256];
  int tid = threadIdx.x;
  int e0 = blockIdx.x * EPB;
  int ne = min(EPB, E - e0);
  if (ne <= 0) return;
  cnt[tid] = 0;
  __syncthreads();
  for (int i = tid; i < ne; i += 256) atomicAdd(&cnt[dst[e0 + i] >> BIN_SHIFT], 1);
  __syncthreads();
  if (tid < 64) {  // exclusive scan cnt[256] -> base
    int carry = 0;
#pragma unroll
    for (int c = 0; c < 4; ++c) {
      int v = cnt[c * 64 + tid];
      int incl = v;
#pragma unroll
      for (int off = 1; off < 64; off <<= 1) {
        int t = __shfl_up(incl, off, 64);
        if (tid >= off) incl += t;
      }
      base[c * 64 + tid] = carry + incl - v;
      carry += __shfl(incl, 63, 64);
    }
  }
  __syncthreads();
  if (tid < nbins && cnt[tid] > 0) gbase[tid] = atomicAdd(&gcur[tid], cnt[tid]);
  cur[tid] = base[tid];
  __syncthreads();
  for (int i = tid; i < ne; i += 256) {
    int d = dst[e0 + i], s = src[e0 + i];
    int p = atomicAdd(&cur[d >> BIN_SHIFT], 1);
    stage[p] = ((uint32_t)(d & (BIN_NODES - 1)) << 23) | (uint32_t)s;
  }
  __syncthreads();
  // recover bin of stage[i] from base[]: i in [base[b], base[b+1]) — find via local dst? simpler: recompute
  for (int i = tid; i < ne; i += 256) {
    uint32_t en = stage[i];
    // bin from position: binary search over base[]
    int lo = 0, hi = 255;
    while (lo < hi) {  // find last b with base[b] <= i
      int mid = (lo + hi + 1) >> 1;
      if (base[mid] <= i) lo = mid; else hi = mid - 1;
    }
    int b = lo;
    int gi = gbase[b] + (i - base[b]);
    if (gi < CAPB) binbuf[(size_t)b * CAPB + gi] = en;
  }
}

// ---------------- pass B: per-bin deg/dis/start + col fill, all dense writes ----------------
__global__ __launch_bounds__(256) void k_passB(
    const uint32_t* __restrict__ binbuf, const int* __restrict__ gcur,
    int* __restrict__ deg, float* __restrict__ dis, int* __restrict__ start,
    int* __restrict__ col, int N, int nbins) {
  __shared__ int hist[512], lstart[512], cur[512];
  __shared__ int colstage[CAPB];                     // 48 KB
  __shared__ int binbase_s;
  int b = blockIdx.x, tid = threadIdx.x;
  int node0 = b << BIN_SHIFT;
  int cnt = min(gcur[b], CAPB);
  hist[tid] = 0; hist[tid + 256] = 0;
  __syncthreads();
  const uint32_t* bp = binbuf + (size_t)b * CAPB;
  for (int i = tid; i < cnt; i += 256) atomicAdd(&hist[bp[i] >> 23], 1);
  __syncthreads();
  if (tid < 64) {
    int s = 0;
    for (int i = tid; i < b; i += 64) s += min(gcur[i], CAPB);
#pragma unroll
    for (int off = 32; off; off >>= 1) s += __shfl_xor(s, off, 64);
    if (tid == 0) binbase_s = s;
    int carry = 0;
#pragma unroll
    for (int c = 0; c < 8; ++c) {
      int v = hist[c * 64 + tid];
      int incl = v;
#pragma unroll
      for (int off = 1; off < 64; off <<= 1) {
        int t = __shfl_up(incl, off, 64);
        if (tid >= off) incl += t;
      }
      lstart[c * 64 + tid] = carry + incl - v;
      carry += __shfl(incl, 63, 64);
    }
  }
  __syncthreads();
  int binbase = binbase_s;
  for (int i = tid; i < 512; i += 256) {
    int node = node0 + i;
    if (node < N) {
      int dg = hist[i];
      deg[node] = dg;
      dis[node] = rsqrtf((float)(dg + 1));
      start[node] = binbase + lstart[i];
    }
  }
  cur[tid] = lstart[tid]; cur[tid + 256] = lstart[tid + 256];
  __syncthreads();
  for (int i = tid; i < cnt; i += 256) {
    uint32_t en = bp[i];
    int p = atomicAdd(&cur[en >> 23], 1);
    colstage[p] = (int)(en & 0x7fffffu);
  }
  __syncthreads();
  for (int i = tid; i < cnt; i += 256) col[binbase + i] = colstage[i];
}

// ---------------- merged weight prep: split W1,W2; fold+split head ----------------
__global__ void k_prep(const float* __restrict__ W1, const float* __restrict__ W2,
                       const float* __restrict__ Wp1, const float* __restrict__ Wp2,
                       const float* __restrict__ bp1, const float* __restrict__ bp2,
                       us* __restrict__ Wt1h, us* __restrict__ Wt1l,
                       us* __restrict__ Wt2h, us* __restrict__ Wt2l,
                       us* __restrict__ Wch, us* __restrict__ Wcl, float* __restrict__ bc) {
  int blk = blockIdx.x, tid = threadIdx.x;
  if (blk < 128) {
    const float* W = (blk < 64) ? W1 : W2;
    us* Wh = (blk < 64) ? Wt1h : Wt2h;
    us* Wl = (blk < 64) ? Wt1l : Wt2l;
    int idx = (blk & 63) * 256 + tid;   // 16384
    int k = idx >> 7, n = idx & 127;
    us h, l;
    split2(W[idx], h, l);
    Wh[n * 128 + k] = h;
    Wl[n * 128 + k] = l;
  } else if (blk < 160) {
    int idx = (blk - 128) * 256 + tid;  // 8192
    int k = idx >> 6, j = idx & 63;
    float acc = 0.f;
    for (int t = 0; t < 128; ++t) acc += Wp1[k * 128 + t] * Wp2[t * 64 + j];
    us h, l;
    split2(acc, h, l);
    Wch[j * 128 + k] = h;
    Wcl[j * 128 + k] = l;
  } else {
    int j = tid;
    if (j < 64) {
      float acc = bp2[j];
      for (int t = 0; t < 128; ++t) acc += bp1[t] * Wp2[t * 64 + j];
      bc[j] = acc;
    }
  }
}

// ---------------- gather one node's aggregated+finalized row, packed bf16x4 ----------------
__device__ __forceinline__ uint2 gather_row(
    const uint2* __restrict__ h2, const int* __restrict__ start,
    const int* __restrict__ deg, const int* __restrict__ col,
    const float* __restrict__ dis, float4 b, int node, int hl) {
  uint2 u = h2[(size_t)node * 32 + hl];
  float ax = bflo(u.x), ay = bfhi(u.x), az = bflo(u.y), aw = bfhi(u.y);
  int e = start[node];
  int e_end = e + deg[node];
  for (; e + 3 < e_end; e += 4) {
    int s0 = col[e], s1 = col[e + 1], s2 = col[e + 2], s3 = col[e + 3];
    uint2 u0 = h2[(size_t)s0 * 32 + hl];
    uint2 u1 = h2[(size_t)s1 * 32 + hl];
    uint2 u2 = h2[(size_t)s2 * 32 + hl];
    uint2 u3 = h2[(size_t)s3 * 32 + hl];
    ax += (bflo(u0.x) + bflo(u1.x)) + (bflo(u2.x) + bflo(u3.x));
    ay += (bfhi(u0.x) + bfhi(u1.x)) + (bfhi(u2.x) + bfhi(u3.x));
    az += (bflo(u0.y) + bflo(u1.y)) + (bflo(u2.y) + bflo(u3.y));
    aw += (bfhi(u0.y) + bfhi(u1.y)) + (bfhi(u2.y) + bfhi(u3.y));
  }
  for (; e < e_end; ++e) {
    uint2 u1 = h2[(size_t)col[e] * 32 + hl];
    ax += bflo(u1.x); ay += bfhi(u1.x); az += bflo(u1.y); aw += bfhi(u1.y);
  }
  float sc = dis[node];
  float rx = fmaxf(ax * sc + b.x, 0.f);
  float ry = fmaxf(ay * sc + b.y, 0.f);
  float rz = fmaxf(az * sc + b.z, 0.f);
  float rw = fmaxf(aw * sc + b.w, 0.f);
  uint2 po;
  po.x = ((uint32_t)f32_to_bf16_rne(ry) << 16) | f32_to_bf16_rne(rx);
  po.y = ((uint32_t)f32_to_bf16_rne(rw) << 16) | f32_to_bf16_rne(rz);
  return po;
}

// ---------------- MFMA GEMM layer1: hbuf = rne_bf16(dis * (x_f32 @ W1)) ----------------
__global__ __launch_bounds__(256) void k_gemm_mfma(
    const float* __restrict__ A, const us* __restrict__ Wh,
    const us* __restrict__ Wl, const float* __restrict__ dis,
    us* __restrict__ out_bf16, int N, int ntiles) {
  __shared__ us As_hi[32 * 136];
  __shared__ us As_lo[32 * 136];
  int tid = threadIdx.x;
  int wave = tid >> 6, lane = tid & 63;
  int n0 = wave * 32;
  int nn = n0 + (lane & 31);
  int khalf = (lane >> 5) * 8;
  int m = lane & 31;

  short8 bh[8], bl[8];
#pragma unroll
  for (int c = 0; c < 8; ++c) {
    bh[c] = *(const short8*)&Wh[nn * 128 + c * 16 + khalf];
    bl[c] = *(const short8*)&Wl[nn * 128 + c * 16 + khalf];
  }

  for (int t = blockIdx.x; t < ntiles; t += gridDim.x) {
    int row0 = t * 32;
    __syncthreads();
    for (int j = tid; j < 1024; j += 256) {
      int r = j >> 5, c = j & 31;
      int row = row0 + r;
      float4 v = make_float4(0.f, 0.f, 0.f, 0.f);
      if (row < N) v = *(const float4*)&A[(size_t)row * 128 + c * 4];
      us h0, h1, h2, h3, l0, l1, l2, l3;
      split2(v.x, h0, l0); split2(v.y, h1, l1);
      split2(v.z, h2, l2); split2(v.w, h3, l3);
      *(ushort4*)&As_hi[r * 136 + c * 4] = make_ushort4(h0, h1, h2, h3);
      *(ushort4*)&As_lo[r * 136 + c * 4] = make_ushort4(l0, l1, l2, l3);
    }
    __syncthreads();

    f32x16 acc = {};
#pragma unroll
    for (int c = 0; c < 8; ++c) {
      short8 ah = *(const short8*)&As_hi[m * 136 + c * 16 + khalf];
      short8 al = *(const short8*)&As_lo[m * 136 + c * 16 + khalf];
      acc = __builtin_amdgcn_mfma_f32_32x32x16_bf16(ah, bh[c], acc, 0, 0, 0);
      acc = __builtin_amdgcn_mfma_f32_32x32x16_bf16(ah, bl[c], acc, 0, 0, 0);
      acc = __builtin_amdgcn_mfma_f32_32x32x16_bf16(al, bh[c], acc, 0, 0, 0);
    }

    int colj = n0 + (lane & 31);
    int rbase = row0 + 4 * (lane >> 5);
#pragma unroll
    for (int reg = 0; reg < 16; ++reg) {
      int row = rbase + (reg & 3) + 8 * (reg >> 2);
      if (row < N) {
        float v = acc[reg] * dis[row];
        out_bf16[(size_t)row * 128 + colj] = f32_to_bf16_rne(v);
      }
    }
  }
}

// ---------------- fused gather(b1,relu) -> MFMA GEMM(W2) -> hbuf2 ----------------
__global__ __launch_bounds__(256) void k_gg(
    const us* __restrict__ h, const us* __restrict__ Wh, const us* __restrict__ Wl,
    const int* __restrict__ start, const int* __restrict__ deg,
    const int* __restrict__ col, const float* __restrict__ dis,
    const float* __restrict__ bias, us* __restrict__ out_bf16, int N, int ntiles) {
  __shared__ us As[32 * 136];
  int tid = threadIdx.x;
  int wave = tid >> 6, lane = tid & 63;
  int n0 = wave * 32;
  int nn = n0 + (lane & 31);
  int khalf = (lane >> 5) * 8;
  int m = lane & 31;
  int hw = tid >> 5, hl = tid & 31;

  short8 bh[8], bl[8];
#pragma unroll
  for (int c = 0; c < 8; ++c) {
    bh[c] = *(const short8*)&Wh[nn * 128 + c * 16 + khalf];
    bl[c] = *(const short8*)&Wl[nn * 128 + c * 16 + khalf];
  }

  const uint2* h2 = (const uint2*)h;
  float4 b = ((const float4*)bias)[hl];

  for (int t = blockIdx.x; t < ntiles; t += gridDim.x) {
    int row0 = t * 32;
    __syncthreads();
#pragma unroll
    for (int i = 0; i < 4; ++i) {
      int r = hw * 4 + i;
      int node = row0 + r;
      uint2 po = make_uint2(0u, 0u);
      if (node < N) po = gather_row(h2, start, deg, col, dis, b, node, hl);
      *(uint2*)&As[r * 136 + hl * 4] = po;
    }
    __syncthreads();

    f32x16 acc = {};
#pragma unroll
    for (int c = 0; c < 8; ++c) {
      short8 ah = *(const short8*)&As[m * 136 + c * 16 + khalf];
      acc = __builtin_amdgcn_mfma_f32_32x32x16_bf16(ah, bh[c], acc, 0, 0, 0);
      acc = __builtin_amdgcn_mfma_f32_32x32x16_bf16(ah, bl[c], acc, 0, 0, 0);
    }

    int colj = n0 + (lane & 31);
    int rbase = row0 + 4 * (lane >> 5);
#pragma unroll
    for (int reg = 0; reg < 16; ++reg) {
      int row = rbase + (reg & 3) + 8 * (reg >> 2);
      if (row < N) {
        float v = acc[reg] * dis[row];
        out_bf16[(size_t)row * 128 + colj] = f32_to_bf16_rne(v);
      }
    }
  }
}

// ---------------- fused gather(b2,relu) -> head MFMA -> log_softmax -> out ----------------
__global__ __launch_bounds__(256) void k_gh(
    const us* __restrict__ h, const us* __restrict__ Wch, const us* __restrict__ Wcl,
    const int* __restrict__ start, const int* __restrict__ deg,
    const int* __restrict__ col, const float* __restrict__ dis,
    const float* __restrict__ bias, const float* __restrict__ bc,
    float* __restrict__ out, int N) {
  __shared__ us As[64 * 136];
  __shared__ float red[2][2][64];
  int tid = threadIdx.x;
  int wave = tid >> 6, lane = tid & 63;
  int rt = wave >> 1, ct = wave & 1;
  int colj = ct * 32 + (lane & 31);
  int khalf = (lane >> 5) * 8;
  int m = lane & 31;
  int hw = tid >> 5, hl = tid & 31;

  short8 bh[8], bl[8];
#pragma unroll
  for (int c = 0; c < 8; ++c) {
    bh[c] = *(const short8*)&Wch[colj * 128 + c * 16 + khalf];
    bl[c] = *(const short8*)&Wcl[colj * 128 + c * 16 + khalf];
  }

  const uint2* h2 = (const uint2*)h;
  float4 b = ((const float4*)bias)[hl];
  int row0 = blockIdx.x * 64;

#pragma unroll
  for (int i = 0; i < 8; ++i) {
    int r = hw * 8 + i;
    int node = row0 + r;
    uint2 po = make_uint2(0u, 0u);
    if (node < N) po = gather_row(h2, start, deg, col, dis, b, node, hl);
    *(uint2*)&As[r * 136 + hl * 4] = po;
  }
  __syncthreads();

  f32x16 acc = {};
  int mrow = rt * 32 + m;
#pragma unroll
  for (int c = 0; c < 8; ++c) {
    short8 ah = *(const short8*)&As[mrow * 136 + c * 16 + khalf];
    acc = __builtin_amdgcn_mfma_f32_32x32x16_bf16(ah, bh[c], acc, 0, 0, 0);
    acc = __builtin_amdgcn_mfma_f32_32x32x16_bf16(ah, bl[c], acc, 0, 0, 0);
  }

  float bcv = bc[colj];
  float lg[16], mx[16];
#pragma unroll
  for (int reg = 0; reg < 16; ++reg) {
    lg[reg] = acc[reg] + bcv;
    float v = lg[reg];
#pragma unroll
    for (int off = 16; off > 0; off >>= 1) v = fmaxf(v, __shfl_xor(v, off, 32));
    mx[reg] = v;
  }
  if ((lane & 31) == 0) {
#pragma unroll
    for (int reg = 0; reg < 16; ++reg) {
      int rl = rt * 32 + (reg & 3) + 8 * (reg >> 2) + 4 * (lane >> 5);
      red[0][ct][rl] = mx[reg];
    }
  }
  __syncthreads();

  float ex[16], sm[16];
#pragma unroll
  for (int reg = 0; reg < 16; ++reg) {
    int rl = rt * 32 + (reg & 3) + 8 * (reg >> 2) + 4 * (lane >> 5);
    float rmax = fmaxf(red[0][0][rl], red[0][1][rl]);
    ex[reg] = lg[reg] - rmax;
    float v = expf(ex[reg]);
#pragma unroll
    for (int off = 16; off > 0; off >>= 1) v += __shfl_xor(v, off, 32);
    sm[reg] = v;
  }
  if ((lane & 31) == 0) {
#pragma unroll
    for (int reg = 0; reg < 16; ++reg) {
      int rl = rt * 32 + (reg & 3) + 8 * (reg >> 2) + 4 * (lane >> 5);
      red[1][ct][rl] = sm[reg];
    }
  }
  __syncthreads();

#pragma unroll
  for (int reg = 0; reg < 16; ++reg) {
    int rl = rt * 32 + (reg & 3) + 8 * (reg >> 2) + 4 * (lane >> 5);
    int row = row0 + rl;
    if (row < N) {
      float total = red[1][0][rl] + red[1][1][rl];
      out[(size_t)row * 64 + colj] = ex[reg] - logf(total);
    }
  }
}

extern "C" void kernel_launch(void* const* d_in, const int* in_sizes, int n_in,
                              void* d_out, int out_size, void* d_ws, size_t ws_size,
                              hipStream_t stream) {
  const float* x   = (const float*)d_in[0];
  const int*   ei  = (const int*)d_in[1];
  const float* W1  = (const float*)d_in[2];
  const float* b1  = (const float*)d_in[3];
  const float* W2  = (const float*)d_in[4];
  const float* b2  = (const float*)d_in[5];
  const float* Wp1 = (const float*)d_in[6];
  const float* bp1 = (const float*)d_in[7];
  const float* Wp2 = (const float*)d_in[8];
  const float* bp2 = (const float*)d_in[9];
  float* out = (float*)d_out;

  int N = in_sizes[0] / 128;
  int E = in_sizes[1] / 2;
  const int* src = ei;
  const int* dst = ei + E;
  int nbins = (N + BIN_NODES - 1) >> BIN_SHIFT;

  // workspace layout (int granularity)
  float* dis   = (float*)d_ws;                    // N
  int*   deg   = (int*)(dis + N);                 // N
  int*   start = deg + N;                         // N
  int*   col   = start + N;                       // E
  int*   gcur  = col + ((E + 3) & ~3);            // 256 (zeroed)
  us* Wt1h = (us*)(gcur + 256);                   // 16384 each
  us* Wt1l = Wt1h + 16384;
  us* Wt2h = Wt1l + 16384;
  us* Wt2l = Wt2h + 16384;
  us* Wch  = Wt2l + 16384;                        // 8192
  us* Wcl  = Wch + 8192;                          // 8192
  float* bc = (float*)(Wcl + 8192);               // 64 (+pad)
  uint32_t* binbuf = (uint32_t*)(bc + 80);        // nbins*CAPB u32 (~9.7 MB)
  us* hbuf  = (us*)(binbuf + (size_t)nbins * CAPB);  // N*128 bf16 = 25.6 MB
  us* hbuf2 = hbuf + (size_t)N * 128;                // N*128 bf16 = 25.6 MB

  hipMemsetAsync(gcur, 0, 256 * sizeof(int), stream);

  int ablocks = (E + EPB - 1) / EPB;
  k_binA<<<ablocks, 256, 0, stream>>>(src, dst, binbuf, gcur, E, nbins);
  k_passB<<<nbins, 256, 0, stream>>>(binbuf, gcur, deg, dis, start, col, N, nbins);
  k_prep<<<161, 256, 0, stream>>>(W1, W2, Wp1, Wp2, bp1, bp2,
                                  Wt1h, Wt1l, Wt2h, Wt2l, Wch, Wcl, bc);

  int ntiles = (N + 31) / 32;
  int gemm_grid = ntiles < 1024 ? ntiles : 1024;
  int hblocks = (N + 63) / 64;

  // layer 1 GEMM (f32 x, split-bf16 MFMA)
  k_gemm_mfma<<<gemm_grid, 256, 0, stream>>>(x, Wt1h, Wt1l, dis, hbuf, N, ntiles);
  // fused: gather(layer1 finalize) + GEMM(W2) -> hbuf2
  k_gg<<<gemm_grid, 256, 0, stream>>>(hbuf, Wt2h, Wt2l, start, deg, col, dis, b1,
                                      hbuf2, N, ntiles);
  // fused: gather(layer2 finalize) + folded head MFMA + log_softmax -> out
  k_gh<<<hblocks, 256, 0, stream>>>(hbuf2, Wch, Wcl, start, deg, col, dis, b2, bc, out, N);
}

// Round 9
// 429.219 us; speedup vs baseline: 1.2121x; 1.2121x over previous
//
#include <hip/hip_runtime.h>
#include <hip/hip_bf16.h>
#include <cstdint>

typedef __attribute__((ext_vector_type(8))) short short8;     // 8 bf16 frag (4 VGPRs)
typedef __attribute__((ext_vector_type(16))) float f32x16;    // 32x32 accumulator
typedef unsigned short us;

#define BIN_SHIFT 9
#define BIN_NODES 512
#define CAPB 12288   // per-bin capacity (mean 8163, +45 sigma)
#define EPB 4096     // edges per binA block

__device__ __forceinline__ float bflo(uint32_t u) { return __builtin_bit_cast(float, u << 16); }
__device__ __forceinline__ float bfhi(uint32_t u) { return __builtin_bit_cast(float, u & 0xffff0000u); }

__device__ __forceinline__ us f32_to_bf16_rne(float f) {
  uint32_t u = __builtin_bit_cast(uint32_t, f);
  u += 0x7fffu + ((u >> 16) & 1u);
  return (us)(u >> 16);
}

__device__ __forceinline__ void split2(float f, us& h, us& l) {
  uint32_t u = __builtin_bit_cast(uint32_t, f);
  h = (us)(u >> 16);
  float fh = __builtin_bit_cast(float, u & 0xffff0000u);
  float r = f - fh;  // exact
  l = (us)(__builtin_bit_cast(uint32_t, r) >> 16);
}

// ---------------- pass A: bin packed (localdst<<23|src) by dst>>9, dense batched appends ----------------
__global__ __launch_bounds__(256) void k_binA(
    const int* __restrict__ src, const int* __restrict__ dst,
    uint32_t* __restrict__ binbuf, int* __restrict__ gcur, int E, int nbins) {
  __shared__ uint32_t stage[EPB];                    // 16 KB
  __shared__ int cnt[256], base[256], cur[256], gbase[256];
  int tid = threadIdx.x;
  int e0 = blockIdx.x * EPB;
  int ne = min(EPB, E - e0);
  if (ne <= 0) return;
  cnt[tid] = 0;
  __syncthreads();
  for (int i = tid; i < ne; i += 256) atomicAdd(&cnt[dst[e0 + i] >> BIN_SHIFT], 1);
  __syncthreads();
  if (tid < 64) {  // exclusive scan cnt[256] -> base
    int carry = 0;
#pragma unroll
    for (int c = 0; c < 4; ++c) {
      int v = cnt[c * 64 + tid];
      int incl = v;
#pragma unroll
      for (int off = 1; off < 64; off <<= 1) {
        int t = __shfl_up(incl, off, 64);
        if (tid >= off) incl += t;
      }
      base[c * 64 + tid] = carry + incl - v;
      carry += __shfl(incl, 63, 64);
    }
  }
  __syncthreads();
  if (tid < nbins && cnt[tid] > 0) gbase[tid] = atomicAdd(&gcur[tid], cnt[tid]);
  cur[tid] = base[tid];
  __syncthreads();
  for (int i = tid; i < ne; i += 256) {
    int d = dst[e0 + i], s = src[e0 + i];
    int p = atomicAdd(&cur[d >> BIN_SHIFT], 1);
    stage[p] = ((uint32_t)(d & (BIN_NODES - 1)) << 23) | (uint32_t)s;
  }
  __syncthreads();
  for (int i = tid; i < ne; i += 256) {
    uint32_t en = stage[i];
    int lo = 0, hi = 255;
    while (lo < hi) {  // last b with base[b] <= i
      int mid = (lo + hi + 1) >> 1;
      if (base[mid] <= i) lo = mid; else hi = mid - 1;
    }
    int b = lo;
    int gi = gbase[b] + (i - base[b]);
    if (gi < CAPB) binbuf[(size_t)b * CAPB + gi] = en;
  }
}

// ---------------- pass B: per-bin deg/dis/start + col fill, all dense writes ----------------
__global__ __launch_bounds__(256) void k_passB(
    const uint32_t* __restrict__ binbuf, const int* __restrict__ gcur,
    int* __restrict__ deg, float* __restrict__ dis, int* __restrict__ start,
    int* __restrict__ col, int N, int nbins) {
  __shared__ int hist[512], lstart[512], cur[512];
  __shared__ int colstage[CAPB];                     // 48 KB
  __shared__ int binbase_s;
  int b = blockIdx.x, tid = threadIdx.x;
  int node0 = b << BIN_SHIFT;
  int cnt = min(gcur[b], CAPB);
  hist[tid] = 0; hist[tid + 256] = 0;
  __syncthreads();
  const uint32_t* bp = binbuf + (size_t)b * CAPB;
  for (int i = tid; i < cnt; i += 256) atomicAdd(&hist[bp[i] >> 23], 1);
  __syncthreads();
  if (tid < 64) {
    int s = 0;
    for (int i = tid; i < b; i += 64) s += min(gcur[i], CAPB);
#pragma unroll
    for (int off = 32; off; off >>= 1) s += __shfl_xor(s, off, 64);
    if (tid == 0) binbase_s = s;
    int carry = 0;
#pragma unroll
    for (int c = 0; c < 8; ++c) {
      int v = hist[c * 64 + tid];
      int incl = v;
#pragma unroll
      for (int off = 1; off < 64; off <<= 1) {
        int t = __shfl_up(incl, off, 64);
        if (tid >= off) incl += t;
      }
      lstart[c * 64 + tid] = carry + incl - v;
      carry += __shfl(incl, 63, 64);
    }
  }
  __syncthreads();
  int binbase = binbase_s;
  for (int i = tid; i < 512; i += 256) {
    int node = node0 + i;
    if (node < N) {
      int dg = hist[i];
      deg[node] = dg;
      dis[node] = rsqrtf((float)(dg + 1));
      start[node] = binbase + lstart[i];
    }
  }
  cur[tid] = lstart[tid]; cur[tid + 256] = lstart[tid + 256];
  __syncthreads();
  for (int i = tid; i < cnt; i += 256) {
    uint32_t en = bp[i];
    int p = atomicAdd(&cur[en >> 23], 1);
    colstage[p] = (int)(en & 0x7fffffu);
  }
  __syncthreads();
  for (int i = tid; i < cnt; i += 256) col[binbase + i] = colstage[i];
}

// ---------------- merged weight prep: split W1,W2; fold+split head ----------------
__global__ void k_prep(const float* __restrict__ W1, const float* __restrict__ W2,
                       const float* __restrict__ Wp1, const float* __restrict__ Wp2,
                       const float* __restrict__ bp1, const float* __restrict__ bp2,
                       us* __restrict__ Wt1h, us* __restrict__ Wt1l,
                       us* __restrict__ Wt2h, us* __restrict__ Wt2l,
                       us* __restrict__ Wch, us* __restrict__ Wcl, float* __restrict__ bc) {
  int blk = blockIdx.x, tid = threadIdx.x;
  if (blk < 128) {
    const float* W = (blk < 64) ? W1 : W2;
    us* Wh = (blk < 64) ? Wt1h : Wt2h;
    us* Wl = (blk < 64) ? Wt1l : Wt2l;
    int idx = (blk & 63) * 256 + tid;   // 16384
    int k = idx >> 7, n = idx & 127;
    us h, l;
    split2(W[idx], h, l);
    Wh[n * 128 + k] = h;
    Wl[n * 128 + k] = l;
  } else if (blk < 160) {
    int idx = (blk - 128) * 256 + tid;  // 8192
    int k = idx >> 6, j = idx & 63;
    float acc = 0.f;
    for (int t = 0; t < 128; ++t) acc += Wp1[k * 128 + t] * Wp2[t * 64 + j];
    us h, l;
    split2(acc, h, l);
    Wch[j * 128 + k] = h;
    Wcl[j * 128 + k] = l;
  } else {
    int j = tid;
    if (j < 64) {
      float acc = bp2[j];
      for (int t = 0; t < 128; ++t) acc += bp1[t] * Wp2[t * 64 + j];
      bc[j] = acc;
    }
  }
}

// ---------------- MFMA GEMM: hbuf = rne_bf16(dis * (A @ W)), one 32-row tile per block ----------------
template <bool AF32>
__global__ __launch_bounds__(256) void k_gemm_mfma(
    const void* __restrict__ Av, const us* __restrict__ Wh,
    const us* __restrict__ Wl, const float* __restrict__ dis,
    us* __restrict__ out_bf16, int N) {
  __shared__ us As_hi[32 * 136];
  __shared__ us As_lo[32 * 136];
  int tid = threadIdx.x;
  int wave = tid >> 6, lane = tid & 63;
  int n0 = wave * 32;
  int nn = n0 + (lane & 31);
  int khalf = (lane >> 5) * 8;
  int m = lane & 31;

  short8 bh[8], bl[8];
#pragma unroll
  for (int c = 0; c < 8; ++c) {
    bh[c] = *(const short8*)&Wh[nn * 128 + c * 16 + khalf];
    bl[c] = *(const short8*)&Wl[nn * 128 + c * 16 + khalf];
  }

  int row0 = blockIdx.x * 32;
  if (AF32) {
    const float* A = (const float*)Av;
    for (int j = tid; j < 1024; j += 256) {
      int r = j >> 5, c = j & 31;
      int row = row0 + r;
      float4 v = make_float4(0.f, 0.f, 0.f, 0.f);
      if (row < N) v = *(const float4*)&A[(size_t)row * 128 + c * 4];
      us h0, h1, h2, h3, l0, l1, l2, l3;
      split2(v.x, h0, l0); split2(v.y, h1, l1);
      split2(v.z, h2, l2); split2(v.w, h3, l3);
      *(ushort4*)&As_hi[r * 136 + c * 4] = make_ushort4(h0, h1, h2, h3);
      *(ushort4*)&As_lo[r * 136 + c * 4] = make_ushort4(l0, l1, l2, l3);
    }
  } else {
    const us* A = (const us*)Av;
    for (int j = tid; j < 512; j += 256) {
      int r = j >> 4, c = j & 15;
      int row = row0 + r;
      uint4 v = make_uint4(0u, 0u, 0u, 0u);
      if (row < N) v = *(const uint4*)&A[(size_t)row * 128 + c * 8];
      *(uint4*)&As_hi[r * 136 + c * 8] = v;
    }
  }
  __syncthreads();

  f32x16 acc = {};
#pragma unroll
  for (int c = 0; c < 8; ++c) {
    short8 ah = *(const short8*)&As_hi[m * 136 + c * 16 + khalf];
    acc = __builtin_amdgcn_mfma_f32_32x32x16_bf16(ah, bh[c], acc, 0, 0, 0);
    acc = __builtin_amdgcn_mfma_f32_32x32x16_bf16(ah, bl[c], acc, 0, 0, 0);
    if (AF32) {
      short8 al = *(const short8*)&As_lo[m * 136 + c * 16 + khalf];
      acc = __builtin_amdgcn_mfma_f32_32x32x16_bf16(al, bh[c], acc, 0, 0, 0);
    }
  }

  int colj = n0 + (lane & 31);
  int rbase = row0 + 4 * (lane >> 5);
#pragma unroll
  for (int reg = 0; reg < 16; ++reg) {
    int row = rbase + (reg & 3) + 8 * (reg >> 2);
    if (row < N) {
      float v = acc[reg] * dis[row];
      out_bf16[(size_t)row * 128 + colj] = f32_to_bf16_rne(v);
    }
  }
}

// ---------------- gather-aggregate (bf16) + fused finalize -> bf16 ----------------
// 16 lanes x uint4 (8 bf16) per node; edge loop unrolled x4 for MLP.
__global__ __launch_bounds__(256) void k_gather(
    const us* __restrict__ h, us* __restrict__ o,
    const int* __restrict__ start, const int* __restrict__ deg,
    const int* __restrict__ col, const float* __restrict__ dis,
    const float* __restrict__ bias, int N) {
  int tid = threadIdx.x;
  int node = blockIdx.x * 16 + (tid >> 4);
  int ln = tid & 15;
  if (node >= N) return;
  const uint4* h4 = (const uint4*)h;  // row = 16 uint4
  uint4 u = h4[(size_t)node * 16 + ln];
  float a0 = bflo(u.x), a1 = bfhi(u.x), a2 = bflo(u.y), a3 = bfhi(u.y);
  float a4 = bflo(u.z), a5 = bfhi(u.z), a6 = bflo(u.w), a7 = bfhi(u.w);
  int e = start[node];
  int e_end = e + deg[node];
  for (; e + 3 < e_end; e += 4) {
    int s0 = col[e], s1 = col[e + 1], s2 = col[e + 2], s3 = col[e + 3];
    uint4 v0 = h4[(size_t)s0 * 16 + ln];
    uint4 v1 = h4[(size_t)s1 * 16 + ln];
    uint4 v2 = h4[(size_t)s2 * 16 + ln];
    uint4 v3 = h4[(size_t)s3 * 16 + ln];
    a0 += (bflo(v0.x) + bflo(v1.x)) + (bflo(v2.x) + bflo(v3.x));
    a1 += (bfhi(v0.x) + bfhi(v1.x)) + (bfhi(v2.x) + bfhi(v3.x));
    a2 += (bflo(v0.y) + bflo(v1.y)) + (bflo(v2.y) + bflo(v3.y));
    a3 += (bfhi(v0.y) + bfhi(v1.y)) + (bfhi(v2.y) + bfhi(v3.y));
    a4 += (bflo(v0.z) + bflo(v1.z)) + (bflo(v2.z) + bflo(v3.z));
    a5 += (bfhi(v0.z) + bfhi(v1.z)) + (bfhi(v2.z) + bfhi(v3.z));
    a6 += (bflo(v0.w) + bflo(v1.w)) + (bflo(v2.w) + bflo(v3.w));
    a7 += (bfhi(v0.w) + bfhi(v1.w)) + (bfhi(v2.w) + bfhi(v3.w));
  }
  for (; e < e_end; ++e) {
    uint4 v0 = h4[(size_t)col[e] * 16 + ln];
    a0 += bflo(v0.x); a1 += bfhi(v0.x); a2 += bflo(v0.y); a3 += bfhi(v0.y);
    a4 += bflo(v0.z); a5 += bfhi(v0.z); a6 += bflo(v0.w); a7 += bfhi(v0.w);
  }
  float sc = dis[node];
  float4 b0 = ((const float4*)bias)[ln * 2];
  float4 b1 = ((const float4*)bias)[ln * 2 + 1];
  float r0 = fmaxf(a0 * sc + b0.x, 0.f), r1 = fmaxf(a1 * sc + b0.y, 0.f);
  float r2 = fmaxf(a2 * sc + b0.z, 0.f), r3 = fmaxf(a3 * sc + b0.w, 0.f);
  float r4 = fmaxf(a4 * sc + b1.x, 0.f), r5 = fmaxf(a5 * sc + b1.y, 0.f);
  float r6 = fmaxf(a6 * sc + b1.z, 0.f), r7 = fmaxf(a7 * sc + b1.w, 0.f);
  uint4 po;
  po.x = ((uint32_t)f32_to_bf16_rne(r1) << 16) | f32_to_bf16_rne(r0);
  po.y = ((uint32_t)f32_to_bf16_rne(r3) << 16) | f32_to_bf16_rne(r2);
  po.z = ((uint32_t)f32_to_bf16_rne(r5) << 16) | f32_to_bf16_rne(r4);
  po.w = ((uint32_t)f32_to_bf16_rne(r7) << 16) | f32_to_bf16_rne(r6);
  ((uint4*)o)[(size_t)node * 16 + ln] = po;
}

// ---------------- head: out = log_softmax(act @ Wc + bc) via MFMA, fused softmax ----------------
__global__ __launch_bounds__(256) void k_head_mfma(
    const us* __restrict__ act, const us* __restrict__ Wch,
    const us* __restrict__ Wcl, const float* __restrict__ bc,
    float* __restrict__ out, int N) {
  __shared__ us As[64 * 136];
  __shared__ float red[2][2][64];
  int tid = threadIdx.x;
  int wave = tid >> 6, lane = tid & 63;
  int rt = wave >> 1, ct = wave & 1;
  int colj = ct * 32 + (lane & 31);
  int khalf = (lane >> 5) * 8;
  int m = lane & 31;

  short8 bh[8], bl[8];
#pragma unroll
  for (int c = 0; c < 8; ++c) {
    bh[c] = *(const short8*)&Wch[colj * 128 + c * 16 + khalf];
    bl[c] = *(const short8*)&Wcl[colj * 128 + c * 16 + khalf];
  }

  int row0 = blockIdx.x * 64;
  for (int j = tid; j < 1024; j += 256) {
    int r = j >> 4, c = j & 15;
    int row = row0 + r;
    uint4 v = make_uint4(0u, 0u, 0u, 0u);
    if (row < N) v = *(const uint4*)&act[(size_t)row * 128 + c * 8];
    *(uint4*)&As[r * 136 + c * 8] = v;
  }
  __syncthreads();

  f32x16 acc = {};
  int mrow = rt * 32 + m;
#pragma unroll
  for (int c = 0; c < 8; ++c) {
    short8 ah = *(const short8*)&As[mrow * 136 + c * 16 + khalf];
    acc = __builtin_amdgcn_mfma_f32_32x32x16_bf16(ah, bh[c], acc, 0, 0, 0);
    acc = __builtin_amdgcn_mfma_f32_32x32x16_bf16(ah, bl[c], acc, 0, 0, 0);
  }

  float bcv = bc[colj];
  float lg[16], mx[16];
#pragma unroll
  for (int reg = 0; reg < 16; ++reg) {
    lg[reg] = acc[reg] + bcv;
    float v = lg[reg];
#pragma unroll
    for (int off = 16; off > 0; off >>= 1) v = fmaxf(v, __shfl_xor(v, off, 32));
    mx[reg] = v;
  }
  if ((lane & 31) == 0) {
#pragma unroll
    for (int reg = 0; reg < 16; ++reg) {
      int rl = rt * 32 + (reg & 3) + 8 * (reg >> 2) + 4 * (lane >> 5);
      red[0][ct][rl] = mx[reg];
    }
  }
  __syncthreads();

  float ex[16], sm[16];
#pragma unroll
  for (int reg = 0; reg < 16; ++reg) {
    int rl = rt * 32 + (reg & 3) + 8 * (reg >> 2) + 4 * (lane >> 5);
    float rmax = fmaxf(red[0][0][rl], red[0][1][rl]);
    ex[reg] = lg[reg] - rmax;
    float v = expf(ex[reg]);
#pragma unroll
    for (int off = 16; off > 0; off >>= 1) v += __shfl_xor(v, off, 32);
    sm[reg] = v;
  }
  if ((lane & 31) == 0) {
#pragma unroll
    for (int reg = 0; reg < 16; ++reg) {
      int rl = rt * 32 + (reg & 3) + 8 * (reg >> 2) + 4 * (lane >> 5);
      red[1][ct][rl] = sm[reg];
    }
  }
  __syncthreads();

#pragma unroll
  for (int reg = 0; reg < 16; ++reg) {
    int rl = rt * 32 + (reg & 3) + 8 * (reg >> 2) + 4 * (lane >> 5);
    int row = row0 + rl;
    if (row < N) {
      float total = red[1][0][rl] + red[1][1][rl];
      out[(size_t)row * 64 + colj] = ex[reg] - logf(total);
    }
  }
}

extern "C" void kernel_launch(void* const* d_in, const int* in_sizes, int n_in,
                              void* d_out, int out_size, void* d_ws, size_t ws_size,
                              hipStream_t stream) {
  const float* x   = (const float*)d_in[0];
  const int*   ei  = (const int*)d_in[1];
  const float* W1  = (const float*)d_in[2];
  const float* b1  = (const float*)d_in[3];
  const float* W2  = (const float*)d_in[4];
  const float* b2  = (const float*)d_in[5];
  const float* Wp1 = (const float*)d_in[6];
  const float* bp1 = (const float*)d_in[7];
  const float* Wp2 = (const float*)d_in[8];
  const float* bp2 = (const float*)d_in[9];
  float* out = (float*)d_out;

  int N = in_sizes[0] / 128;
  int E = in_sizes[1] / 2;
  const int* src = ei;
  const int* dst = ei + E;
  int nbins = (N + BIN_NODES - 1) >> BIN_SHIFT;

  // workspace layout (int granularity)
  float* dis   = (float*)d_ws;                    // N
  int*   deg   = (int*)(dis + N);                 // N
  int*   start = deg + N;                         // N
  int*   col   = start + N;                       // E
  int*   gcur  = col + ((E + 3) & ~3);            // 256 (zeroed)
  us* Wt1h = (us*)(gcur + 256);                   // 16384 each
  us* Wt1l = Wt1h + 16384;
  us* Wt2h = Wt1l + 16384;
  us* Wt2l = Wt2h + 16384;
  us* Wch  = Wt2l + 16384;                        // 8192
  us* Wcl  = Wch + 8192;                          // 8192
  float* bc = (float*)(Wcl + 8192);               // 64 (+pad)
  uint32_t* binbuf = (uint32_t*)(bc + 80);        // nbins*CAPB u32 (~9.7 MB)
  us* hbuf = (us*)(binbuf + (size_t)nbins * CAPB);  // N*128 bf16 = 25.6 MB
  us* act  = hbuf + (size_t)N * 128;                // N*128 bf16 = 25.6 MB

  hipMemsetAsync(gcur, 0, 256 * sizeof(int), stream);

  int ablocks = (E + EPB - 1) / EPB;
  k_binA<<<ablocks, 256, 0, stream>>>(src, dst, binbuf, gcur, E, nbins);
  k_passB<<<nbins, 256, 0, stream>>>(binbuf, gcur, deg, dis, start, col, N, nbins);
  k_prep<<<161, 256, 0, stream>>>(W1, W2, Wp1, Wp2, bp1, bp2,
                                  Wt1h, Wt1l, Wt2h, Wt2l, Wch, Wcl, bc);

  int ntiles = (N + 31) / 32;
  int agblocks = (N + 15) / 16;
  int hblocks = (N + 63) / 64;

  // layer 1
  k_gemm_mfma<true><<<ntiles, 256, 0, stream>>>(x, Wt1h, Wt1l, dis, hbuf, N);
  k_gather<<<agblocks, 256, 0, stream>>>(hbuf, act, start, deg, col, dis, b1, N);
  // layer 2
  k_gemm_mfma<false><<<ntiles, 256, 0, stream>>>(act, Wt2h, Wt2l, dis, hbuf, N);
  k_gather<<<agblocks, 256, 0, stream>>>(hbuf, act, start, deg, col, dis, b2, N);
  // folded head
  k_head_mfma<<<hblocks, 256, 0, stream>>>(act, Wch, Wcl, bc, out, N);
}